// Round 1
// baseline (4396.884 us; speedup 1.0000x reference)
//
#include <hip/hip_runtime.h>

// 2-layer GCN (PyG GCNConv semantics): add self-loops, D^-1/2 (A+I) D^-1/2,
// linear-then-aggregate. Baseline implementation: atomic scatter-add per edge.
//
// Workspace layout (all re-zeroed each launch; harness poisons ws with 0xAA):
//   deg  : N int32    (in-degree counts, excludes self-loop; +1 at rsqrt time)
//   dinv : N float    (rsqrt(deg+1))
//   agg1 : N*8 float  (layer-1 edge aggregation, then in-place ReLU'd h1)
// Total 10*N*4 = 20 MB.

#define THREADS 256

__global__ void deg_kernel(const int* __restrict__ dst, int* __restrict__ deg, int E) {
    int e = blockIdx.x * blockDim.x + threadIdx.x;
    if (e < E) atomicAdd(&deg[dst[e]], 1);
}

__global__ void dinv_kernel(const int* __restrict__ deg, float* __restrict__ dinv, int N) {
    int i = blockIdx.x * blockDim.x + threadIdx.x;
    if (i < N) dinv[i] = rsqrtf((float)(deg[i] + 1));   // +1 = self-loop
}

// Layer-1 edge scatter: msg = (x[src] @ W1) * dinv[src]*dinv[dst] -> agg1[dst]
__global__ void scatter1_kernel(const int* __restrict__ ei,      // [2*E]: src then dst
                                const float* __restrict__ x,     // [N,3]
                                const float* __restrict__ W1,    // [3,8] row-major
                                const float* __restrict__ dinv,
                                float* __restrict__ agg1,        // [N,8]
                                int E) {
    int e = blockIdx.x * blockDim.x + threadIdx.x;
    if (e >= E) return;
    int s = ei[e];
    int d = ei[E + e];
    float norm = dinv[s] * dinv[d];
    float x0 = x[3 * s], x1 = x[3 * s + 1], x2 = x[3 * s + 2];
#pragma unroll
    for (int k = 0; k < 8; ++k) {
        float m = x0 * W1[k] + x1 * W1[8 + k] + x2 * W1[16 + k];
        atomicAdd(&agg1[(size_t)d * 8 + k], m * norm);
    }
}

// Layer-1 finalize: h1 = relu(agg1 + (x@W1)*dinv^2 + b1), in place.
__global__ void finalize1_kernel(const float* __restrict__ x,
                                 const float* __restrict__ W1,
                                 const float* __restrict__ b1,
                                 const float* __restrict__ dinv,
                                 float* __restrict__ agg1,
                                 int N) {
    int i = blockIdx.x * blockDim.x + threadIdx.x;
    if (i >= N) return;
    float di = dinv[i];
    float d2 = di * di;
    float x0 = x[3 * i], x1 = x[3 * i + 1], x2 = x[3 * i + 2];
    float4* p = (float4*)(agg1 + (size_t)i * 8);
    float4 a = p[0], b = p[1];
    float v[8] = {a.x, a.y, a.z, a.w, b.x, b.y, b.z, b.w};
#pragma unroll
    for (int k = 0; k < 8; ++k) {
        float m = x0 * W1[k] + x1 * W1[8 + k] + x2 * W1[16 + k];
        v[k] = fmaxf(v[k] + m * d2 + b1[k], 0.0f);
    }
    p[0] = make_float4(v[0], v[1], v[2], v[3]);
    p[1] = make_float4(v[4], v[5], v[6], v[7]);
}

// Layer-2 edge scatter: msg = (h1[src] @ W2) * norm -> out[dst]
__global__ void scatter2_kernel(const int* __restrict__ ei,
                                const float* __restrict__ h1,    // [N,8]
                                const float* __restrict__ W2,    // [8,2] row-major
                                const float* __restrict__ dinv,
                                float* __restrict__ out,         // [N,2]
                                int E) {
    int e = blockIdx.x * blockDim.x + threadIdx.x;
    if (e >= E) return;
    int s = ei[e];
    int d = ei[E + e];
    float norm = dinv[s] * dinv[d];
    const float4* hp = (const float4*)(h1 + (size_t)s * 8);
    float4 a = hp[0], b = hp[1];
    float h[8] = {a.x, a.y, a.z, a.w, b.x, b.y, b.z, b.w};
    float m0 = 0.f, m1 = 0.f;
#pragma unroll
    for (int k = 0; k < 8; ++k) {
        m0 += h[k] * W2[2 * k];
        m1 += h[k] * W2[2 * k + 1];
    }
    atomicAdd(&out[(size_t)d * 2],     m0 * norm);
    atomicAdd(&out[(size_t)d * 2 + 1], m1 * norm);
}

// Layer-2 finalize: out += (h1@W2)*dinv^2 + b2
__global__ void finalize2_kernel(const float* __restrict__ h1,
                                 const float* __restrict__ W2,
                                 const float* __restrict__ b2,
                                 const float* __restrict__ dinv,
                                 float* __restrict__ out,
                                 int N) {
    int i = blockIdx.x * blockDim.x + threadIdx.x;
    if (i >= N) return;
    float di = dinv[i];
    float d2 = di * di;
    const float4* hp = (const float4*)(h1 + (size_t)i * 8);
    float4 a = hp[0], b = hp[1];
    float h[8] = {a.x, a.y, a.z, a.w, b.x, b.y, b.z, b.w};
    float m0 = 0.f, m1 = 0.f;
#pragma unroll
    for (int k = 0; k < 8; ++k) {
        m0 += h[k] * W2[2 * k];
        m1 += h[k] * W2[2 * k + 1];
    }
    out[(size_t)i * 2]     += m0 * d2 + b2[0];
    out[(size_t)i * 2 + 1] += m1 * d2 + b2[1];
}

extern "C" void kernel_launch(void* const* d_in, const int* in_sizes, int n_in,
                              void* d_out, int out_size, void* d_ws, size_t ws_size,
                              hipStream_t stream) {
    const float* x  = (const float*)d_in[0];
    const int*   ei = (const int*)d_in[1];   // [2, E] flattened: src row then dst row
    const float* W1 = (const float*)d_in[2];
    const float* b1 = (const float*)d_in[3];
    const float* W2 = (const float*)d_in[4];
    const float* b2 = (const float*)d_in[5];
    float* out = (float*)d_out;

    const int N = in_sizes[0] / 3;
    const int E = in_sizes[1] / 2;

    char* ws = (char*)d_ws;
    int*   deg  = (int*)ws;
    float* dinv = (float*)(ws + (size_t)N * 4);
    float* agg1 = (float*)(ws + (size_t)N * 8);   // N*8 floats, 16B-aligned

    // Zero accumulators (harness poisons ws/out with 0xAA each replay).
    hipMemsetAsync(deg,  0, (size_t)N * 4, stream);
    hipMemsetAsync(agg1, 0, (size_t)N * 32, stream);
    hipMemsetAsync(out,  0, (size_t)out_size * 4, stream);

    const int eb = (E + THREADS - 1) / THREADS;
    const int nb = (N + THREADS - 1) / THREADS;

    deg_kernel<<<eb, THREADS, 0, stream>>>(ei + E, deg, E);
    dinv_kernel<<<nb, THREADS, 0, stream>>>(deg, dinv, N);
    scatter1_kernel<<<eb, THREADS, 0, stream>>>(ei, x, W1, dinv, agg1, E);
    finalize1_kernel<<<nb, THREADS, 0, stream>>>(x, W1, b1, dinv, agg1, N);
    scatter2_kernel<<<eb, THREADS, 0, stream>>>(ei, agg1, W2, dinv, out, E);
    finalize2_kernel<<<nb, THREADS, 0, stream>>>(agg1, W2, b2, dinv, out, N);
}

// Round 2
// 963.274 us; speedup vs baseline: 4.5645x; 4.5645x over previous
//
#include <hip/hip_runtime.h>

// 2-layer GCN via dst-sorted CSR + segmented sums (atomics only in the 8M-edge
// histogram). Decomposition:
//   y[i] = (x[i]@W1)*dinv[i]                       [N,8]
//   h1[d] = relu(dinv[d]*(sum_{s in N(d)} y[s] + y[d]) + b1)
//   z[i]  = (h1[i]@W2)*dinv[i]                     [N,2]
//   out[d] = dinv[d]*(sum_{s in N(d)} z[s] + z[d]) + b2
//
// Workspace (~74 MB): deg[N] i32, rowptr[N+4] i32, bsum[512] i32, dinv[N] f32,
// z[2N] f32, y[8N] f32, rank[E] u16, sorted_src[E] i32.

#define THREADS 256
#define SCAN_CHUNK 1024   // elements per scan block (256 thr x 4)

__global__ void hist_kernel(const int* __restrict__ dst, int* __restrict__ deg,
                            unsigned short* __restrict__ rank, int E) {
    int e = blockIdx.x * blockDim.x + threadIdx.x;
    if (e < E) rank[e] = (unsigned short)atomicAdd(&deg[dst[e]], 1);
}

// dinv = rsqrt(deg+1); y = (x@W1)*dinv
__global__ void dinv_y_kernel(const int* __restrict__ deg, const float* __restrict__ x,
                              const float* __restrict__ W1, float* __restrict__ dinv,
                              float* __restrict__ y, int N) {
    int i = blockIdx.x * blockDim.x + threadIdx.x;
    if (i >= N) return;
    float di = rsqrtf((float)(deg[i] + 1));
    dinv[i] = di;
    float x0 = x[3 * i], x1 = x[3 * i + 1], x2 = x[3 * i + 2];
    float4* yp = (float4*)(y + (size_t)i * 8);
    float v[8];
#pragma unroll
    for (int k = 0; k < 8; ++k)
        v[k] = (x0 * W1[k] + x1 * W1[8 + k] + x2 * W1[16 + k]) * di;
    yp[0] = make_float4(v[0], v[1], v[2], v[3]);
    yp[1] = make_float4(v[4], v[5], v[6], v[7]);
}

// Pass 1: per-block local exclusive scan (1024 elems/block) + block sums.
__global__ void scan1_kernel(const int* __restrict__ deg, int* __restrict__ rowptr,
                             int* __restrict__ bsum, int N) {
    __shared__ int sdata[256];
    int t = threadIdx.x;
    int base = blockIdx.x * SCAN_CHUNK + t * 4;
    int v[4];
#pragma unroll
    for (int k = 0; k < 4; ++k) { int i = base + k; v[k] = (i < N) ? deg[i] : 0; }
    int s = v[0] + v[1] + v[2] + v[3];
    sdata[t] = s;
    __syncthreads();
    for (int off = 1; off < 256; off <<= 1) {
        int xv = (t >= off) ? sdata[t - off] : 0;
        __syncthreads();
        sdata[t] += xv;
        __syncthreads();
    }
    if (t == 255) bsum[blockIdx.x] = sdata[255];
    int run = sdata[t] - s;   // exclusive prefix within block
#pragma unroll
    for (int k = 0; k < 4; ++k) { int i = base + k; if (i < N) rowptr[i] = run; run += v[k]; }
}

// Pass 2: single-block exclusive scan of block sums (nb <= 512).
__global__ void scan2_kernel(int* __restrict__ bsum, int nb) {
    __shared__ int sdata[512];
    int t = threadIdx.x;
    int v = (t < nb) ? bsum[t] : 0;
    sdata[t] = v;
    __syncthreads();
    for (int off = 1; off < 512; off <<= 1) {
        int xv = (t >= off) ? sdata[t - off] : 0;
        __syncthreads();
        sdata[t] += xv;
        __syncthreads();
    }
    if (t < nb) bsum[t] = sdata[t] - v;   // exclusive
}

// Pass 3: add block offsets; set rowptr[N] = E.
__global__ void scan3_kernel(int* __restrict__ rowptr, const int* __restrict__ bsum,
                             int N, int E) {
    int i = blockIdx.x * blockDim.x + threadIdx.x;
    if (i < N) rowptr[i] += bsum[i / SCAN_CHUNK];
    if (i == 0) rowptr[N] = E;
}

// Atomic-free edge sort: sorted_src[rowptr[dst]+rank] = src
__global__ void scatter_kernel(const int* __restrict__ ei, const unsigned short* __restrict__ rank,
                               const int* __restrict__ rowptr, int* __restrict__ sorted_src, int E) {
    int e = blockIdx.x * blockDim.x + threadIdx.x;
    if (e >= E) return;
    int s = ei[e];
    int d = ei[E + e];
    sorted_src[rowptr[d] + (int)rank[e]] = s;
}

// Per-node segmented sum of y[src]; fused finalize-1 + z computation.
__global__ void gather1_kernel(const int* __restrict__ rowptr, const int* __restrict__ sorted_src,
                               const float* __restrict__ y, const float* __restrict__ dinv,
                               const float* __restrict__ b1, const float* __restrict__ W2,
                               float* __restrict__ z, int N) {
    int i = blockIdx.x * blockDim.x + threadIdx.x;
    if (i >= N) return;
    int beg = rowptr[i], end = rowptr[i + 1];
    float acc[8] = {0, 0, 0, 0, 0, 0, 0, 0};
    for (int j = beg; j < end; ++j) {
        int s = sorted_src[j];
        const float4* yp = (const float4*)(y + (size_t)s * 8);
        float4 a = yp[0], b = yp[1];
        acc[0] += a.x; acc[1] += a.y; acc[2] += a.z; acc[3] += a.w;
        acc[4] += b.x; acc[5] += b.y; acc[6] += b.z; acc[7] += b.w;
    }
    float di = dinv[i];
    const float4* yp = (const float4*)(y + (size_t)i * 8);
    float4 a = yp[0], b = yp[1];
    float self[8] = {a.x, a.y, a.z, a.w, b.x, b.y, b.z, b.w};
    float m0 = 0.f, m1 = 0.f;
#pragma unroll
    for (int k = 0; k < 8; ++k) {
        float h = fmaxf(di * (acc[k] + self[k]) + b1[k], 0.0f);   // h1[i][k]
        m0 += h * W2[2 * k];
        m1 += h * W2[2 * k + 1];
    }
    z[(size_t)i * 2]     = m0 * di;
    z[(size_t)i * 2 + 1] = m1 * di;
}

// Per-node segmented sum of z[src]; fused finalize-2 -> out.
__global__ void gather2_kernel(const int* __restrict__ rowptr, const int* __restrict__ sorted_src,
                               const float* __restrict__ z, const float* __restrict__ dinv,
                               const float* __restrict__ b2, float* __restrict__ out, int N) {
    int i = blockIdx.x * blockDim.x + threadIdx.x;
    if (i >= N) return;
    int beg = rowptr[i], end = rowptr[i + 1];
    float a0 = 0.f, a1 = 0.f;
    for (int j = beg; j < end; ++j) {
        int s = sorted_src[j];
        const float2 zv = *(const float2*)(z + (size_t)s * 2);
        a0 += zv.x; a1 += zv.y;
    }
    float di = dinv[i];
    const float2 zs = *(const float2*)(z + (size_t)i * 2);
    out[(size_t)i * 2]     = di * (a0 + zs.x) + b2[0];
    out[(size_t)i * 2 + 1] = di * (a1 + zs.y) + b2[1];
}

extern "C" void kernel_launch(void* const* d_in, const int* in_sizes, int n_in,
                              void* d_out, int out_size, void* d_ws, size_t ws_size,
                              hipStream_t stream) {
    const float* x  = (const float*)d_in[0];
    const int*   ei = (const int*)d_in[1];   // [2, E] flat (int32 per harness): src row, dst row
    const float* W1 = (const float*)d_in[2];
    const float* b1 = (const float*)d_in[3];
    const float* W2 = (const float*)d_in[4];
    const float* b2 = (const float*)d_in[5];
    float* out = (float*)d_out;

    const int N = in_sizes[0] / 3;
    const int E = in_sizes[1] / 2;

    // Workspace carve-up (16B-aligned segments).
    char* ws = (char*)d_ws;
    size_t off = 0;
    int* deg = (int*)(ws + off);               off += (size_t)N * 4;
    int* rowptr = (int*)(ws + off);            off += ((size_t)N + 4) * 4;
    int* bsum = (int*)(ws + off);              off += 512 * 4;
    float* dinv = (float*)(ws + off);          off += (size_t)N * 4;
    float* z = (float*)(ws + off);             off += (size_t)N * 8;
    float* y = (float*)(ws + off);             off += (size_t)N * 32;
    unsigned short* rank = (unsigned short*)(ws + off); off += (size_t)E * 2;
    int* sorted_src = (int*)(ws + off);        off += (size_t)E * 4;
    (void)ws_size;

    hipMemsetAsync(deg, 0, (size_t)N * 4, stream);

    const int eb = (E + THREADS - 1) / THREADS;
    const int nb = (N + THREADS - 1) / THREADS;
    const int sb = (N + SCAN_CHUNK - 1) / SCAN_CHUNK;   // scan blocks (489 <= 512)

    hist_kernel<<<eb, THREADS, 0, stream>>>(ei + E, deg, rank, E);
    dinv_y_kernel<<<nb, THREADS, 0, stream>>>(deg, x, W1, dinv, y, N);
    scan1_kernel<<<sb, 256, 0, stream>>>(deg, rowptr, bsum, N);
    scan2_kernel<<<1, 512, 0, stream>>>(bsum, sb);
    scan3_kernel<<<nb, THREADS, 0, stream>>>(rowptr, bsum, N, E);
    scatter_kernel<<<eb, THREADS, 0, stream>>>(ei, rank, rowptr, sorted_src, E);
    gather1_kernel<<<nb, THREADS, 0, stream>>>(rowptr, sorted_src, y, dinv, b1, W2, z, N);
    gather2_kernel<<<nb, THREADS, 0, stream>>>(rowptr, sorted_src, z, dinv, b2, out, N);
}

// Round 3
// 945.380 us; speedup vs baseline: 4.6509x; 1.0189x over previous
//
#include <hip/hip_runtime.h>

// 2-layer GCN via dst-sorted CSR + segmented sums (atomics only in the 8M-edge
// histogram). Linearity trick: aggregate 3-wide xd[s]=x[s]*dinv[s] (padded to
// float4) and apply W1 AFTER aggregation -> halves layer-1 gather traffic.
//   h1[d] = relu(dinv[d]*((sum_{s in N(d)} xd[s] + xd[d]) @ W1) + b1)
//   z[i]  = (h1[i]@W2)*dinv[i]                     [N,2]
//   out[d] = dinv[d]*(sum_{s in N(d)} z[s] + z[d]) + b2
//
// Workspace (~66 MB): deg[N] i32, rowptr[N+4] i32, bsum[512] i32, dinv[N] f32,
// z[2N] f32, xd4[4N] f32, rank[E] u16, sorted_src[E] i32.

#define THREADS 256
#define SCAN_CHUNK 1024   // elements per scan block (256 thr x 4)

__global__ void hist_kernel(const int* __restrict__ dst, int* __restrict__ deg,
                            unsigned short* __restrict__ rank, int E) {
    int e = blockIdx.x * blockDim.x + threadIdx.x;
    if (e < E) rank[e] = (unsigned short)atomicAdd(&deg[dst[e]], 1);
}

// dinv = rsqrt(deg+1); xd4 = {x*dinv, pad}
__global__ void dinv_xd_kernel(const int* __restrict__ deg, const float* __restrict__ x,
                               float* __restrict__ dinv, float4* __restrict__ xd4, int N) {
    int i = blockIdx.x * blockDim.x + threadIdx.x;
    if (i >= N) return;
    float di = rsqrtf((float)(deg[i] + 1));
    dinv[i] = di;
    float x0 = x[3 * i], x1 = x[3 * i + 1], x2 = x[3 * i + 2];
    xd4[i] = make_float4(x0 * di, x1 * di, x2 * di, 0.0f);
}

// Pass 1: per-block local exclusive scan (1024 elems/block) + block sums.
__global__ void scan1_kernel(const int* __restrict__ deg, int* __restrict__ rowptr,
                             int* __restrict__ bsum, int N) {
    __shared__ int sdata[256];
    int t = threadIdx.x;
    int base = blockIdx.x * SCAN_CHUNK + t * 4;
    int v[4];
#pragma unroll
    for (int k = 0; k < 4; ++k) { int i = base + k; v[k] = (i < N) ? deg[i] : 0; }
    int s = v[0] + v[1] + v[2] + v[3];
    sdata[t] = s;
    __syncthreads();
    for (int off = 1; off < 256; off <<= 1) {
        int xv = (t >= off) ? sdata[t - off] : 0;
        __syncthreads();
        sdata[t] += xv;
        __syncthreads();
    }
    if (t == 255) bsum[blockIdx.x] = sdata[255];
    int run = sdata[t] - s;   // exclusive prefix within block
#pragma unroll
    for (int k = 0; k < 4; ++k) { int i = base + k; if (i < N) rowptr[i] = run; run += v[k]; }
}

// Pass 2: single-block exclusive scan of block sums (nb <= 512).
__global__ void scan2_kernel(int* __restrict__ bsum, int nb) {
    __shared__ int sdata[512];
    int t = threadIdx.x;
    int v = (t < nb) ? bsum[t] : 0;
    sdata[t] = v;
    __syncthreads();
    for (int off = 1; off < 512; off <<= 1) {
        int xv = (t >= off) ? sdata[t - off] : 0;
        __syncthreads();
        sdata[t] += xv;
        __syncthreads();
    }
    if (t < nb) bsum[t] = sdata[t] - v;   // exclusive
}

// Pass 3: add block offsets; set rowptr[N] = E.
__global__ void scan3_kernel(int* __restrict__ rowptr, const int* __restrict__ bsum,
                             int N, int E) {
    int i = blockIdx.x * blockDim.x + threadIdx.x;
    if (i < N) rowptr[i] += bsum[i / SCAN_CHUNK];
    if (i == 0) rowptr[N] = E;
}

// Atomic-free edge sort: sorted_src[rowptr[dst]+rank] = src
__global__ void scatter_kernel(const int* __restrict__ ei, const unsigned short* __restrict__ rank,
                               const int* __restrict__ rowptr, int* __restrict__ sorted_src, int E) {
    int e = blockIdx.x * blockDim.x + threadIdx.x;
    if (e >= E) return;
    int s = ei[e];
    int d = ei[E + e];
    sorted_src[rowptr[d] + (int)rank[e]] = s;
}

// Per-node segmented sum of xd4[src]; epilogue applies W1, relu, W2 -> z.
__global__ void gather1_kernel(const int* __restrict__ rowptr, const int* __restrict__ sorted_src,
                               const float4* __restrict__ xd4, const float* __restrict__ dinv,
                               const float* __restrict__ W1, const float* __restrict__ b1,
                               const float* __restrict__ W2, float* __restrict__ z, int N) {
    int i = blockIdx.x * blockDim.x + threadIdx.x;
    if (i >= N) return;
    int beg = rowptr[i], end = rowptr[i + 1];
    float a0 = 0.f, a1 = 0.f, a2 = 0.f;
    for (int j = beg; j < end; ++j) {
        int s = sorted_src[j];
        const float4 v = xd4[s];
        a0 += v.x; a1 += v.y; a2 += v.z;
    }
    const float4 self = xd4[i];
    a0 += self.x; a1 += self.y; a2 += self.z;
    float di = dinv[i];
    a0 *= di; a1 *= di; a2 *= di;
    float m0 = 0.f, m1 = 0.f;
#pragma unroll
    for (int k = 0; k < 8; ++k) {
        float h = fmaxf(a0 * W1[k] + a1 * W1[8 + k] + a2 * W1[16 + k] + b1[k], 0.0f);
        m0 += h * W2[2 * k];
        m1 += h * W2[2 * k + 1];
    }
    z[(size_t)i * 2]     = m0 * di;
    z[(size_t)i * 2 + 1] = m1 * di;
}

// Per-node segmented sum of z[src]; fused finalize-2 -> out.
__global__ void gather2_kernel(const int* __restrict__ rowptr, const int* __restrict__ sorted_src,
                               const float* __restrict__ z, const float* __restrict__ dinv,
                               const float* __restrict__ b2, float* __restrict__ out, int N) {
    int i = blockIdx.x * blockDim.x + threadIdx.x;
    if (i >= N) return;
    int beg = rowptr[i], end = rowptr[i + 1];
    float a0 = 0.f, a1 = 0.f;
    for (int j = beg; j < end; ++j) {
        int s = sorted_src[j];
        const float2 zv = *(const float2*)(z + (size_t)s * 2);
        a0 += zv.x; a1 += zv.y;
    }
    float di = dinv[i];
    const float2 zs = *(const float2*)(z + (size_t)i * 2);
    out[(size_t)i * 2]     = di * (a0 + zs.x) + b2[0];
    out[(size_t)i * 2 + 1] = di * (a1 + zs.y) + b2[1];
}

extern "C" void kernel_launch(void* const* d_in, const int* in_sizes, int n_in,
                              void* d_out, int out_size, void* d_ws, size_t ws_size,
                              hipStream_t stream) {
    const float* x  = (const float*)d_in[0];
    const int*   ei = (const int*)d_in[1];   // [2, E] flat: src row, dst row
    const float* W1 = (const float*)d_in[2];
    const float* b1 = (const float*)d_in[3];
    const float* W2 = (const float*)d_in[4];
    const float* b2 = (const float*)d_in[5];
    float* out = (float*)d_out;

    const int N = in_sizes[0] / 3;
    const int E = in_sizes[1] / 2;

    // Workspace carve-up (16B-aligned segments).
    char* ws = (char*)d_ws;
    size_t off = 0;
    int* deg = (int*)(ws + off);               off += (size_t)N * 4;
    int* rowptr = (int*)(ws + off);            off += ((size_t)N + 4) * 4;
    int* bsum = (int*)(ws + off);              off += 512 * 4;
    float* dinv = (float*)(ws + off);          off += (size_t)N * 4;
    float* z = (float*)(ws + off);             off += (size_t)N * 8;
    float4* xd4 = (float4*)(ws + off);         off += (size_t)N * 16;
    unsigned short* rank = (unsigned short*)(ws + off); off += (size_t)E * 2;
    int* sorted_src = (int*)(ws + off);        off += (size_t)E * 4;
    (void)ws_size;

    hipMemsetAsync(deg, 0, (size_t)N * 4, stream);

    const int eb = (E + THREADS - 1) / THREADS;
    const int nb = (N + THREADS - 1) / THREADS;
    const int sb = (N + SCAN_CHUNK - 1) / SCAN_CHUNK;   // scan blocks (489 <= 512)

    hist_kernel<<<eb, THREADS, 0, stream>>>(ei + E, deg, rank, E);
    dinv_xd_kernel<<<nb, THREADS, 0, stream>>>(deg, x, dinv, xd4, N);
    scan1_kernel<<<sb, 256, 0, stream>>>(deg, rowptr, bsum, N);
    scan2_kernel<<<1, 512, 0, stream>>>(bsum, sb);
    scan3_kernel<<<nb, THREADS, 0, stream>>>(rowptr, bsum, N, E);
    scatter_kernel<<<eb, THREADS, 0, stream>>>(ei, rank, rowptr, sorted_src, E);
    gather1_kernel<<<nb, THREADS, 0, stream>>>(rowptr, sorted_src, xd4, dinv, W1, b1, W2, z, N);
    gather2_kernel<<<nb, THREADS, 0, stream>>>(rowptr, sorted_src, z, dinv, b2, out, N);
}

// Round 4
// 512.511 us; speedup vs baseline: 8.5791x; 1.8446x over previous
//
#include <hip/hip_runtime.h>

// 2-layer GCN via bucketed counting sort + LDS-accumulated aggregation.
// Nodes bucketed by dst>>9 (512 nodes/bucket, NBK=ceil(N/512)<=1024 buckets).
// Edge record packed in u32: rec = (src<<9) | (dst&511)  (src < 2^23).
//
// Pipeline (zero global atomics; LDS atomics only):
//   A  bucket_count  : per-block LDS hist over buckets -> histM[bucket][blockA]
//   B1 colscan       : exclusive scan of histM rows (across blocks) + totals
//   B2 bucketscan    : exclusive scan of totals -> bucketPtr
//   C  bucket_scatter: place recs via bucketPtr + colPrefix + LDS cursor
//   D  deg_dinv_xd   : per-bucket LDS hist -> deg; dinv=rsqrt(deg+1); xd4=x*dinv
//   E  agg1          : edge-parallel LDS float accumulation of xd4[src];
//                      epilogue: self + W1 + ReLU + W2 -> z[i] (float2)
//   F  agg2          : same over z[src]; epilogue -> out
//
// Math: h1[d] = relu(dinv[d]*((sum_nbr xd[s] + xd[d])@W1) + b1)
//       z[i]  = (h1[i]@W2)*dinv[i]
//       out[d]= dinv[d]*(sum_nbr z[s] + z[d]) + b2
//
// Requires NBK<=1024 and NBA<=1024 (holds for N=500K, E=8M with CH=8192).

#define SHIFT 9
#define BSZ   512              // nodes per bucket
#define CH    8192             // edges per block in passes A/C
#define NBK_MAX 1024

__global__ void bucket_count_kernel(const int* __restrict__ dst, int* __restrict__ histM,
                                    int E, int NBA, int NBK) {
    __shared__ int lhist[NBK_MAX];
    int t = threadIdx.x;
    for (int b = t; b < NBK; b += 256) lhist[b] = 0;
    __syncthreads();
    int base = blockIdx.x * CH;
#pragma unroll
    for (int k = 0; k < CH / 256; ++k) {
        int e = base + t + k * 256;
        if (e < E) atomicAdd(&lhist[dst[e] >> SHIFT], 1);
    }
    __syncthreads();
    for (int b = t; b < NBK; b += 256)
        histM[(size_t)b * NBA + blockIdx.x] = lhist[b];
}

// Exclusive scan of one bucket's row histM[bk][0..NBA-1] in place; totals[bk]=sum.
__global__ void colscan_kernel(int* __restrict__ histM, int* __restrict__ totals,
                               int NBA) {
    __shared__ int sdata[256];
    int t = threadIdx.x;
    size_t base = (size_t)blockIdx.x * NBA;
    int v[4];
#pragma unroll
    for (int k = 0; k < 4; ++k) { int i = t * 4 + k; v[k] = (i < NBA) ? histM[base + i] : 0; }
    int s = v[0] + v[1] + v[2] + v[3];
    sdata[t] = s;
    __syncthreads();
    for (int off = 1; off < 256; off <<= 1) {
        int xv = (t >= off) ? sdata[t - off] : 0;
        __syncthreads();
        sdata[t] += xv;
        __syncthreads();
    }
    if (t == 255) totals[blockIdx.x] = sdata[255];
    int run = sdata[t] - s;
#pragma unroll
    for (int k = 0; k < 4; ++k) { int i = t * 4 + k; if (i < NBA) histM[base + i] = run; run += v[k]; }
}

// Exclusive scan of totals[NBK] -> bucketPtr; bucketPtr[NBK]=E.
__global__ void bucketscan_kernel(const int* __restrict__ totals, int* __restrict__ bucketPtr,
                                  int NBK, int E) {
    __shared__ int sdata[256];
    int t = threadIdx.x;
    int v[4];
#pragma unroll
    for (int k = 0; k < 4; ++k) { int i = t * 4 + k; v[k] = (i < NBK) ? totals[i] : 0; }
    int s = v[0] + v[1] + v[2] + v[3];
    sdata[t] = s;
    __syncthreads();
    for (int off = 1; off < 256; off <<= 1) {
        int xv = (t >= off) ? sdata[t - off] : 0;
        __syncthreads();
        sdata[t] += xv;
        __syncthreads();
    }
    int run = sdata[t] - s;
#pragma unroll
    for (int k = 0; k < 4; ++k) { int i = t * 4 + k; if (i < NBK) bucketPtr[i] = run; run += v[k]; }
    if (t == 255) bucketPtr[NBK] = E;
}

__global__ void bucket_scatter_kernel(const int* __restrict__ ei, const int* __restrict__ histM,
                                      const int* __restrict__ bucketPtr,
                                      unsigned int* __restrict__ sorted,
                                      int E, int NBA, int NBK) {
    __shared__ int cur[NBK_MAX];
    int t = threadIdx.x;
    for (int b = t; b < NBK; b += 256)
        cur[b] = bucketPtr[b] + histM[(size_t)b * NBA + blockIdx.x];
    __syncthreads();
    int base = blockIdx.x * CH;
#pragma unroll
    for (int k = 0; k < CH / 256; ++k) {
        int e = base + t + k * 256;
        if (e < E) {
            int s = ei[e];
            int d = ei[E + e];
            int pos = atomicAdd(&cur[d >> SHIFT], 1);
            sorted[pos] = ((unsigned int)s << SHIFT) | (unsigned int)(d & (BSZ - 1));
        }
    }
}

// Per-bucket: deg via LDS hist; dinv = rsqrt(deg+1); xd4 = {x*dinv, 0}.
__global__ void deg_dinv_xd_kernel(const unsigned int* __restrict__ sorted,
                                   const int* __restrict__ bucketPtr,
                                   const float* __restrict__ x,
                                   float* __restrict__ dinv, float4* __restrict__ xd4,
                                   int N) {
    __shared__ int lhist[BSZ];
    int t = threadIdx.x;
    int bk = blockIdx.x;
    for (int l = t; l < BSZ; l += 256) lhist[l] = 0;
    __syncthreads();
    int beg = bucketPtr[bk], end = bucketPtr[bk + 1];
    for (int j = beg + t; j < end; j += 256)
        atomicAdd(&lhist[sorted[j] & (BSZ - 1)], 1);
    __syncthreads();
    for (int l = t; l < BSZ; l += 256) {
        int i = (bk << SHIFT) + l;
        if (i < N) {
            float di = rsqrtf((float)(lhist[l] + 1));
            dinv[i] = di;
            float x0 = x[3 * i], x1 = x[3 * i + 1], x2 = x[3 * i + 2];
            xd4[i] = make_float4(x0 * di, x1 * di, x2 * di, 0.0f);
        }
    }
}

// Layer-1 aggregation + fused epilogue -> z.
__global__ void agg1_kernel(const unsigned int* __restrict__ sorted,
                            const int* __restrict__ bucketPtr,
                            const float4* __restrict__ xd4, const float* __restrict__ dinv,
                            const float* __restrict__ W1, const float* __restrict__ b1,
                            const float* __restrict__ W2, float* __restrict__ z, int N) {
    __shared__ float a0[BSZ], a1[BSZ], a2[BSZ];
    int t = threadIdx.x;
    int bk = blockIdx.x;
    for (int l = t; l < BSZ; l += 256) { a0[l] = 0.f; a1[l] = 0.f; a2[l] = 0.f; }
    __syncthreads();
    int beg = bucketPtr[bk], end = bucketPtr[bk + 1];
    for (int j = beg + t; j < end; j += 256) {
        unsigned int rec = sorted[j];
        int s = rec >> SHIFT;
        int ld = rec & (BSZ - 1);
        float4 v = xd4[s];
        atomicAdd(&a0[ld], v.x);
        atomicAdd(&a1[ld], v.y);
        atomicAdd(&a2[ld], v.z);
    }
    __syncthreads();
    for (int l = t; l < BSZ; l += 256) {
        int i = (bk << SHIFT) + l;
        if (i < N) {
            float di = dinv[i];
            float4 self = xd4[i];
            float s0 = (a0[l] + self.x) * di;
            float s1 = (a1[l] + self.y) * di;
            float s2 = (a2[l] + self.z) * di;
            float m0 = 0.f, m1 = 0.f;
#pragma unroll
            for (int k = 0; k < 8; ++k) {
                float h = fmaxf(s0 * W1[k] + s1 * W1[8 + k] + s2 * W1[16 + k] + b1[k], 0.0f);
                m0 += h * W2[2 * k];
                m1 += h * W2[2 * k + 1];
            }
            z[(size_t)i * 2]     = m0 * di;
            z[(size_t)i * 2 + 1] = m1 * di;
        }
    }
}

// Layer-2 aggregation + fused epilogue -> out.
__global__ void agg2_kernel(const unsigned int* __restrict__ sorted,
                            const int* __restrict__ bucketPtr,
                            const float* __restrict__ z, const float* __restrict__ dinv,
                            const float* __restrict__ b2, float* __restrict__ out, int N) {
    __shared__ float a0[BSZ], a1[BSZ];
    int t = threadIdx.x;
    int bk = blockIdx.x;
    for (int l = t; l < BSZ; l += 256) { a0[l] = 0.f; a1[l] = 0.f; }
    __syncthreads();
    int beg = bucketPtr[bk], end = bucketPtr[bk + 1];
    for (int j = beg + t; j < end; j += 256) {
        unsigned int rec = sorted[j];
        int s = rec >> SHIFT;
        int ld = rec & (BSZ - 1);
        float2 zv = *(const float2*)(z + (size_t)s * 2);
        atomicAdd(&a0[ld], zv.x);
        atomicAdd(&a1[ld], zv.y);
    }
    __syncthreads();
    for (int l = t; l < BSZ; l += 256) {
        int i = (bk << SHIFT) + l;
        if (i < N) {
            float di = dinv[i];
            const float2 zs = *(const float2*)(z + (size_t)i * 2);
            out[(size_t)i * 2]     = di * (a0[l] + zs.x) + b2[0];
            out[(size_t)i * 2 + 1] = di * (a1[l] + zs.y) + b2[1];
        }
    }
}

extern "C" void kernel_launch(void* const* d_in, const int* in_sizes, int n_in,
                              void* d_out, int out_size, void* d_ws, size_t ws_size,
                              hipStream_t stream) {
    const float* x  = (const float*)d_in[0];
    const int*   ei = (const int*)d_in[1];   // [2, E] flat: src row, dst row
    const float* W1 = (const float*)d_in[2];
    const float* b1 = (const float*)d_in[3];
    const float* W2 = (const float*)d_in[4];
    const float* b2 = (const float*)d_in[5];
    float* out = (float*)d_out;

    const int N = in_sizes[0] / 3;
    const int E = in_sizes[1] / 2;
    const int NBK = (N + BSZ - 1) / BSZ;       // 977 buckets
    const int NBA = (E + CH - 1) / CH;         // 977 blocks in A/C

    // Workspace carve-up (every byte written before read; no memsets needed).
    char* ws = (char*)d_ws;
    size_t off = 0;
    auto alloc = [&](size_t bytes) { char* p = ws + off; off = (off + bytes + 15) & ~(size_t)15; return p; };
    int* histM           = (int*)alloc((size_t)NBK * NBA * 4);
    int* totals          = (int*)alloc((size_t)NBK * 4);
    int* bucketPtr       = (int*)alloc(((size_t)NBK + 1) * 4);
    float* dinv          = (float*)alloc((size_t)N * 4);
    float* z             = (float*)alloc((size_t)N * 8);
    float4* xd4          = (float4*)alloc((size_t)N * 16);
    unsigned int* sorted = (unsigned int*)alloc((size_t)E * 4);
    (void)ws_size;

    bucket_count_kernel<<<NBA, 256, 0, stream>>>(ei + E, histM, E, NBA, NBK);
    colscan_kernel<<<NBK, 256, 0, stream>>>(histM, totals, NBA);
    bucketscan_kernel<<<1, 256, 0, stream>>>(totals, bucketPtr, NBK, E);
    bucket_scatter_kernel<<<NBA, 256, 0, stream>>>(ei, histM, bucketPtr, sorted, E, NBA, NBK);
    deg_dinv_xd_kernel<<<NBK, 256, 0, stream>>>(sorted, bucketPtr, x, dinv, xd4, N);
    agg1_kernel<<<NBK, 256, 0, stream>>>(sorted, bucketPtr, xd4, dinv, W1, b1, W2, z, N);
    agg2_kernel<<<NBK, 256, 0, stream>>>(sorted, bucketPtr, z, dinv, b2, out, N);
}

// Round 5
// 488.139 us; speedup vs baseline: 9.0074x; 1.0499x over previous
//
#include <hip/hip_runtime.h>

// 2-layer GCN via bucketed counting sort + LDS-accumulated aggregation.
// Nodes bucketed by dst>>11 (2048 nodes/bucket, NBK=245). Bucket count chosen
// so the scatter pass's active write-cursor working set (~blocks_per_XCD x NBK
// x 64B lines ~ 1.9 MB) fits per-XCD L2 -> partial sectors merge before
// eviction (R4 with 977 buckets: 7.6 MB > 4 MB L2 -> WRITE_SIZE 214 MB).
// Edge record packed in u32: rec = (src<<11) | (dst&2047)  (src < 2^19).
//
// Pipeline (zero global atomics; LDS atomics only):
//   A  bucket_count  : per-block LDS hist (4-way sub-hist) -> histM[bk][blockA]
//   B1 colscan       : exclusive scan of histM rows (across blocks) + totals
//   B2 bucketscan    : exclusive scan of totals -> bucketPtr
//   C  bucket_scatter: place recs via bucketPtr + colPrefix + LDS cursor
//   D  deg_dinv_xd   : per-bucket LDS hist -> deg; dinv=rsqrt(deg+1); xd4=x*dinv
//   E  agg1          : edge-parallel LDS float accumulation of xd4[src];
//                      epilogue: self + W1 + ReLU + W2 -> z[i] (float2)
//   F  agg2          : same over z[src]; epilogue -> out

#define SHIFT 11
#define BSZ   2048             // nodes per bucket
#define CH    8192             // edges per block in passes A/C
#define NBK_MAX 256
#define AGG_THREADS 512

__global__ void bucket_count_kernel(const int* __restrict__ dst, int* __restrict__ histM,
                                    int E, int NBA, int NBK) {
    __shared__ int lhist[4 * NBK_MAX];
    int t = threadIdx.x;
    for (int b = t; b < 4 * NBK; b += 256) lhist[b] = 0;
    __syncthreads();
    int sub = t & 3;
    int base = blockIdx.x * CH;
#pragma unroll
    for (int k = 0; k < CH / 256; ++k) {
        int e = base + t + k * 256;
        if (e < E) atomicAdd(&lhist[((dst[e] >> SHIFT) << 2) | sub], 1);
    }
    __syncthreads();
    for (int b = t; b < NBK; b += 256)
        histM[(size_t)b * NBA + blockIdx.x] =
            lhist[4 * b] + lhist[4 * b + 1] + lhist[4 * b + 2] + lhist[4 * b + 3];
}

// Exclusive scan of one bucket's row histM[bk][0..NBA-1] in place; totals[bk]=sum.
__global__ void colscan_kernel(int* __restrict__ histM, int* __restrict__ totals,
                               int NBA) {
    __shared__ int sdata[256];
    int t = threadIdx.x;
    size_t base = (size_t)blockIdx.x * NBA;
    int v[4];
#pragma unroll
    for (int k = 0; k < 4; ++k) { int i = t * 4 + k; v[k] = (i < NBA) ? histM[base + i] : 0; }
    int s = v[0] + v[1] + v[2] + v[3];
    sdata[t] = s;
    __syncthreads();
    for (int off = 1; off < 256; off <<= 1) {
        int xv = (t >= off) ? sdata[t - off] : 0;
        __syncthreads();
        sdata[t] += xv;
        __syncthreads();
    }
    if (t == 255) totals[blockIdx.x] = sdata[255];
    int run = sdata[t] - s;
#pragma unroll
    for (int k = 0; k < 4; ++k) { int i = t * 4 + k; if (i < NBA) histM[base + i] = run; run += v[k]; }
}

// Exclusive scan of totals[NBK] -> bucketPtr; bucketPtr[NBK]=E.
__global__ void bucketscan_kernel(const int* __restrict__ totals, int* __restrict__ bucketPtr,
                                  int NBK, int E) {
    __shared__ int sdata[256];
    int t = threadIdx.x;
    int v[4];
#pragma unroll
    for (int k = 0; k < 4; ++k) { int i = t * 4 + k; v[k] = (i < NBK) ? totals[i] : 0; }
    int s = v[0] + v[1] + v[2] + v[3];
    sdata[t] = s;
    __syncthreads();
    for (int off = 1; off < 256; off <<= 1) {
        int xv = (t >= off) ? sdata[t - off] : 0;
        __syncthreads();
        sdata[t] += xv;
        __syncthreads();
    }
    int run = sdata[t] - s;
#pragma unroll
    for (int k = 0; k < 4; ++k) { int i = t * 4 + k; if (i < NBK) bucketPtr[i] = run; run += v[k]; }
    if (t == 255) bucketPtr[NBK] = E;
}

__global__ void bucket_scatter_kernel(const int* __restrict__ ei, const int* __restrict__ histM,
                                      const int* __restrict__ bucketPtr,
                                      unsigned int* __restrict__ sorted,
                                      int E, int NBA, int NBK) {
    __shared__ int cur[NBK_MAX];
    int t = threadIdx.x;
    for (int b = t; b < NBK; b += 256)
        cur[b] = bucketPtr[b] + histM[(size_t)b * NBA + blockIdx.x];
    __syncthreads();
    int base = blockIdx.x * CH;
#pragma unroll
    for (int k = 0; k < CH / 256; ++k) {
        int e = base + t + k * 256;
        if (e < E) {
            int s = ei[e];
            int d = ei[E + e];
            int pos = atomicAdd(&cur[d >> SHIFT], 1);
            sorted[pos] = ((unsigned int)s << SHIFT) | (unsigned int)(d & (BSZ - 1));
        }
    }
}

// Per-bucket: deg via LDS hist; dinv = rsqrt(deg+1); xd4 = {x*dinv, 0}.
__global__ void deg_dinv_xd_kernel(const unsigned int* __restrict__ sorted,
                                   const int* __restrict__ bucketPtr,
                                   const float* __restrict__ x,
                                   float* __restrict__ dinv, float4* __restrict__ xd4,
                                   int N) {
    __shared__ int lhist[BSZ];
    int t = threadIdx.x;
    int bk = blockIdx.x;
    for (int l = t; l < BSZ; l += AGG_THREADS) lhist[l] = 0;
    __syncthreads();
    int beg = bucketPtr[bk], end = bucketPtr[bk + 1];
    for (int j = beg + t; j < end; j += AGG_THREADS)
        atomicAdd(&lhist[sorted[j] & (BSZ - 1)], 1);
    __syncthreads();
    for (int l = t; l < BSZ; l += AGG_THREADS) {
        int i = (bk << SHIFT) + l;
        if (i < N) {
            float di = rsqrtf((float)(lhist[l] + 1));
            dinv[i] = di;
            float x0 = x[3 * i], x1 = x[3 * i + 1], x2 = x[3 * i + 2];
            xd4[i] = make_float4(x0 * di, x1 * di, x2 * di, 0.0f);
        }
    }
}

// Layer-1 aggregation + fused epilogue -> z.
__global__ void agg1_kernel(const unsigned int* __restrict__ sorted,
                            const int* __restrict__ bucketPtr,
                            const float4* __restrict__ xd4, const float* __restrict__ dinv,
                            const float* __restrict__ W1, const float* __restrict__ b1,
                            const float* __restrict__ W2, float* __restrict__ z, int N) {
    __shared__ float a0[BSZ], a1[BSZ], a2[BSZ];
    int t = threadIdx.x;
    int bk = blockIdx.x;
    for (int l = t; l < BSZ; l += AGG_THREADS) { a0[l] = 0.f; a1[l] = 0.f; a2[l] = 0.f; }
    __syncthreads();
    int beg = bucketPtr[bk], end = bucketPtr[bk + 1];
    for (int j = beg + t; j < end; j += AGG_THREADS) {
        unsigned int rec = sorted[j];
        int s = rec >> SHIFT;
        int ld = rec & (BSZ - 1);
        float4 v = xd4[s];
        atomicAdd(&a0[ld], v.x);
        atomicAdd(&a1[ld], v.y);
        atomicAdd(&a2[ld], v.z);
    }
    __syncthreads();
    for (int l = t; l < BSZ; l += AGG_THREADS) {
        int i = (bk << SHIFT) + l;
        if (i < N) {
            float di = dinv[i];
            float4 self = xd4[i];
            float s0 = (a0[l] + self.x) * di;
            float s1 = (a1[l] + self.y) * di;
            float s2 = (a2[l] + self.z) * di;
            float m0 = 0.f, m1 = 0.f;
#pragma unroll
            for (int k = 0; k < 8; ++k) {
                float h = fmaxf(s0 * W1[k] + s1 * W1[8 + k] + s2 * W1[16 + k] + b1[k], 0.0f);
                m0 += h * W2[2 * k];
                m1 += h * W2[2 * k + 1];
            }
            z[(size_t)i * 2]     = m0 * di;
            z[(size_t)i * 2 + 1] = m1 * di;
        }
    }
}

// Layer-2 aggregation + fused epilogue -> out.
__global__ void agg2_kernel(const unsigned int* __restrict__ sorted,
                            const int* __restrict__ bucketPtr,
                            const float* __restrict__ z, const float* __restrict__ dinv,
                            const float* __restrict__ b2, float* __restrict__ out, int N) {
    __shared__ float a0[BSZ], a1[BSZ];
    int t = threadIdx.x;
    int bk = blockIdx.x;
    for (int l = t; l < BSZ; l += AGG_THREADS) { a0[l] = 0.f; a1[l] = 0.f; }
    __syncthreads();
    int beg = bucketPtr[bk], end = bucketPtr[bk + 1];
    for (int j = beg + t; j < end; j += AGG_THREADS) {
        unsigned int rec = sorted[j];
        int s = rec >> SHIFT;
        int ld = rec & (BSZ - 1);
        float2 zv = *(const float2*)(z + (size_t)s * 2);
        atomicAdd(&a0[ld], zv.x);
        atomicAdd(&a1[ld], zv.y);
    }
    __syncthreads();
    for (int l = t; l < BSZ; l += AGG_THREADS) {
        int i = (bk << SHIFT) + l;
        if (i < N) {
            float di = dinv[i];
            const float2 zs = *(const float2*)(z + (size_t)i * 2);
            out[(size_t)i * 2]     = di * (a0[l] + zs.x) + b2[0];
            out[(size_t)i * 2 + 1] = di * (a1[l] + zs.y) + b2[1];
        }
    }
}

extern "C" void kernel_launch(void* const* d_in, const int* in_sizes, int n_in,
                              void* d_out, int out_size, void* d_ws, size_t ws_size,
                              hipStream_t stream) {
    const float* x  = (const float*)d_in[0];
    const int*   ei = (const int*)d_in[1];   // [2, E] flat: src row, dst row
    const float* W1 = (const float*)d_in[2];
    const float* b1 = (const float*)d_in[3];
    const float* W2 = (const float*)d_in[4];
    const float* b2 = (const float*)d_in[5];
    float* out = (float*)d_out;

    const int N = in_sizes[0] / 3;
    const int E = in_sizes[1] / 2;
    const int NBK = (N + BSZ - 1) / BSZ;       // 245 buckets
    const int NBA = (E + CH - 1) / CH;         // 977 blocks in A/C

    // Workspace carve-up (every byte written before read; no memsets needed).
    char* ws = (char*)d_ws;
    size_t off = 0;
    auto alloc = [&](size_t bytes) { char* p = ws + off; off = (off + bytes + 15) & ~(size_t)15; return p; };
    int* histM           = (int*)alloc((size_t)NBK * NBA * 4);
    int* totals          = (int*)alloc((size_t)NBK * 4);
    int* bucketPtr       = (int*)alloc(((size_t)NBK + 1) * 4);
    float* dinv          = (float*)alloc((size_t)N * 4);
    float* z             = (float*)alloc((size_t)N * 8);
    float4* xd4          = (float4*)alloc((size_t)N * 16);
    unsigned int* sorted = (unsigned int*)alloc((size_t)E * 4);
    (void)ws_size;

    bucket_count_kernel<<<NBA, 256, 0, stream>>>(ei + E, histM, E, NBA, NBK);
    colscan_kernel<<<NBK, 256, 0, stream>>>(histM, totals, NBA);
    bucketscan_kernel<<<1, 256, 0, stream>>>(totals, bucketPtr, NBK, E);
    bucket_scatter_kernel<<<NBA, 256, 0, stream>>>(ei, histM, bucketPtr, sorted, E, NBA, NBK);
    deg_dinv_xd_kernel<<<NBK, AGG_THREADS, 0, stream>>>(sorted, bucketPtr, x, dinv, xd4, N);
    agg1_kernel<<<NBK, AGG_THREADS, 0, stream>>>(sorted, bucketPtr, xd4, dinv, W1, b1, W2, z, N);
    agg2_kernel<<<NBK, AGG_THREADS, 0, stream>>>(sorted, bucketPtr, z, dinv, b2, out, N);
}

// Round 6
// 472.078 us; speedup vs baseline: 9.3139x; 1.0340x over previous
//
#include <hip/hip_runtime.h>

// 2-layer GCN via bucketed counting sort + split-K LDS aggregation.
// Nodes bucketed by dst>>11 (2048/bucket, NBK=245; chosen in R5 so scatter's
// write-cursor working set fits per-XCD L2). R6: per-bucket passes were
// 245-block latency-bound (21.9% occupancy) -> each bucket now gets SPLIT=4
// blocks, each accumulating a quarter of the bucket's edges into LDS and
// storing a partial (plain coalesced stores); N-parallel epilogues combine.
// Edge record u32: rec = (src<<11) | (dst&2047)  (src < 2^19).
//
// Pipeline (zero global atomics; LDS atomics only):
//   A  bucket_count   : per-block LDS hist (4-way sub-hist) -> histM[bk][blkA]
//   B1 colscan        : exclusive scan of histM rows + totals
//   B2 bucketscan     : exclusive scan of totals -> bucketPtr
//   C  bucket_scatter : place recs via bucketPtr + colPrefix + LDS cursor
//   D1 deg_partial    : split-K LDS hist -> partialD[sp][node]
//   D2 dinv_xd        : deg=sum partials; dinv=rsqrt(deg+1); xd4=x*dinv
//   E1 agg1_partial   : split-K LDS float accum of xd4[src] -> partial1
//   E2 z_epilogue     : sum partials + self; W1+ReLU+W2 -> z
//   F1 agg2_partial   : split-K LDS accum of z[src] -> partial2
//   F2 out_epilogue   : sum partials + self -> out
//
// Math: h1[d] = relu(dinv[d]*((sum_nbr xd[s] + xd[d])@W1) + b1)
//       z[i]  = (h1[i]@W2)*dinv[i]
//       out[d]= dinv[d]*(sum_nbr z[s] + z[d]) + b2

#define SHIFT 11
#define BSZ   2048             // nodes per bucket
#define CH    8192             // edges per block in passes A/C
#define NBK_MAX 256
#define AGG_THREADS 512
#define SPLIT 4                // sub-blocks per bucket in D1/E1/F1

__global__ void bucket_count_kernel(const int* __restrict__ dst, int* __restrict__ histM,
                                    int E, int NBA, int NBK) {
    __shared__ int lhist[4 * NBK_MAX];
    int t = threadIdx.x;
    for (int b = t; b < 4 * NBK; b += 256) lhist[b] = 0;
    __syncthreads();
    int sub = t & 3;
    int base = blockIdx.x * CH;
#pragma unroll
    for (int k = 0; k < CH / 256; ++k) {
        int e = base + t + k * 256;
        if (e < E) atomicAdd(&lhist[((dst[e] >> SHIFT) << 2) | sub], 1);
    }
    __syncthreads();
    for (int b = t; b < NBK; b += 256)
        histM[(size_t)b * NBA + blockIdx.x] =
            lhist[4 * b] + lhist[4 * b + 1] + lhist[4 * b + 2] + lhist[4 * b + 3];
}

// Exclusive scan of one bucket's row histM[bk][0..NBA-1] in place; totals[bk]=sum.
__global__ void colscan_kernel(int* __restrict__ histM, int* __restrict__ totals,
                               int NBA) {
    __shared__ int sdata[256];
    int t = threadIdx.x;
    size_t base = (size_t)blockIdx.x * NBA;
    int v[4];
#pragma unroll
    for (int k = 0; k < 4; ++k) { int i = t * 4 + k; v[k] = (i < NBA) ? histM[base + i] : 0; }
    int s = v[0] + v[1] + v[2] + v[3];
    sdata[t] = s;
    __syncthreads();
    for (int off = 1; off < 256; off <<= 1) {
        int xv = (t >= off) ? sdata[t - off] : 0;
        __syncthreads();
        sdata[t] += xv;
        __syncthreads();
    }
    if (t == 255) totals[blockIdx.x] = sdata[255];
    int run = sdata[t] - s;
#pragma unroll
    for (int k = 0; k < 4; ++k) { int i = t * 4 + k; if (i < NBA) histM[base + i] = run; run += v[k]; }
}

// Exclusive scan of totals[NBK] -> bucketPtr; bucketPtr[NBK]=E.
__global__ void bucketscan_kernel(const int* __restrict__ totals, int* __restrict__ bucketPtr,
                                  int NBK, int E) {
    __shared__ int sdata[256];
    int t = threadIdx.x;
    int v[4];
#pragma unroll
    for (int k = 0; k < 4; ++k) { int i = t * 4 + k; v[k] = (i < NBK) ? totals[i] : 0; }
    int s = v[0] + v[1] + v[2] + v[3];
    sdata[t] = s;
    __syncthreads();
    for (int off = 1; off < 256; off <<= 1) {
        int xv = (t >= off) ? sdata[t - off] : 0;
        __syncthreads();
        sdata[t] += xv;
        __syncthreads();
    }
    int run = sdata[t] - s;
#pragma unroll
    for (int k = 0; k < 4; ++k) { int i = t * 4 + k; if (i < NBK) bucketPtr[i] = run; run += v[k]; }
    if (t == 255) bucketPtr[NBK] = E;
}

__global__ void bucket_scatter_kernel(const int* __restrict__ ei, const int* __restrict__ histM,
                                      const int* __restrict__ bucketPtr,
                                      unsigned int* __restrict__ sorted,
                                      int E, int NBA, int NBK) {
    __shared__ int cur[NBK_MAX];
    int t = threadIdx.x;
    for (int b = t; b < NBK; b += 256)
        cur[b] = bucketPtr[b] + histM[(size_t)b * NBA + blockIdx.x];
    __syncthreads();
    int base = blockIdx.x * CH;
#pragma unroll
    for (int k = 0; k < CH / 256; ++k) {
        int e = base + t + k * 256;
        if (e < E) {
            int s = ei[e];
            int d = ei[E + e];
            int pos = atomicAdd(&cur[d >> SHIFT], 1);
            sorted[pos] = ((unsigned int)s << SHIFT) | (unsigned int)(d & (BSZ - 1));
        }
    }
}

// D1: split-K per-node degree histogram -> partialD[sp][node].
__global__ void deg_partial_kernel(const unsigned int* __restrict__ sorted,
                                   const int* __restrict__ bucketPtr,
                                   int* __restrict__ partialD, int N) {
    __shared__ int lhist[BSZ];
    int t = threadIdx.x;
    int bk = blockIdx.x >> 2, sp = blockIdx.x & 3;
    for (int l = t; l < BSZ; l += AGG_THREADS) lhist[l] = 0;
    __syncthreads();
    int beg = bucketPtr[bk], end = bucketPtr[bk + 1], len = end - beg;
    int s0 = beg + (int)(((long long)len * sp) >> 2);
    int s1 = beg + (int)(((long long)len * (sp + 1)) >> 2);
    for (int j = s0 + t; j < s1; j += AGG_THREADS)
        atomicAdd(&lhist[sorted[j] & (BSZ - 1)], 1);
    __syncthreads();
    size_t base = (size_t)sp * N;
    for (int l = t; l < BSZ; l += AGG_THREADS) {
        int i = (bk << SHIFT) + l;
        if (i < N) partialD[base + i] = lhist[l];
    }
}

// D2: deg = sum of partials; dinv = rsqrt(deg+1); xd4 = {x*dinv, 0}.
__global__ void dinv_xd_kernel(const int* __restrict__ partialD, const float* __restrict__ x,
                               float* __restrict__ dinv, float4* __restrict__ xd4, int N) {
    int i = blockIdx.x * blockDim.x + threadIdx.x;
    if (i >= N) return;
    int deg = partialD[i] + partialD[(size_t)N + i] +
              partialD[2 * (size_t)N + i] + partialD[3 * (size_t)N + i];
    float di = rsqrtf((float)(deg + 1));
    dinv[i] = di;
    float x0 = x[3 * i], x1 = x[3 * i + 1], x2 = x[3 * i + 2];
    xd4[i] = make_float4(x0 * di, x1 * di, x2 * di, 0.0f);
}

// E1: split-K LDS accumulation of xd4[src] -> partial1[sp][node] (float4).
__global__ void agg1_partial_kernel(const unsigned int* __restrict__ sorted,
                                    const int* __restrict__ bucketPtr,
                                    const float4* __restrict__ xd4,
                                    float4* __restrict__ partial1, int N) {
    __shared__ float a0[BSZ], a1[BSZ], a2[BSZ];
    int t = threadIdx.x;
    int bk = blockIdx.x >> 2, sp = blockIdx.x & 3;
    for (int l = t; l < BSZ; l += AGG_THREADS) { a0[l] = 0.f; a1[l] = 0.f; a2[l] = 0.f; }
    __syncthreads();
    int beg = bucketPtr[bk], end = bucketPtr[bk + 1], len = end - beg;
    int s0 = beg + (int)(((long long)len * sp) >> 2);
    int s1 = beg + (int)(((long long)len * (sp + 1)) >> 2);
    for (int j = s0 + t; j < s1; j += AGG_THREADS) {
        unsigned int rec = sorted[j];
        int s = rec >> SHIFT;
        int ld = rec & (BSZ - 1);
        float4 v = xd4[s];
        atomicAdd(&a0[ld], v.x);
        atomicAdd(&a1[ld], v.y);
        atomicAdd(&a2[ld], v.z);
    }
    __syncthreads();
    size_t base = (size_t)sp * N;
    for (int l = t; l < BSZ; l += AGG_THREADS) {
        int i = (bk << SHIFT) + l;
        if (i < N) partial1[base + i] = make_float4(a0[l], a1[l], a2[l], 0.0f);
    }
}

// E2: sum partials + self; fused W1 + ReLU + W2 -> z.
__global__ void z_epilogue_kernel(const float4* __restrict__ partial1,
                                  const float4* __restrict__ xd4, const float* __restrict__ dinv,
                                  const float* __restrict__ W1, const float* __restrict__ b1,
                                  const float* __restrict__ W2, float* __restrict__ z, int N) {
    int i = blockIdx.x * blockDim.x + threadIdx.x;
    if (i >= N) return;
    float4 p0 = partial1[i];
    float4 p1 = partial1[(size_t)N + i];
    float4 p2 = partial1[2 * (size_t)N + i];
    float4 p3 = partial1[3 * (size_t)N + i];
    float4 self = xd4[i];
    float di = dinv[i];
    float s0 = (p0.x + p1.x + p2.x + p3.x + self.x) * di;
    float s1 = (p0.y + p1.y + p2.y + p3.y + self.y) * di;
    float s2 = (p0.z + p1.z + p2.z + p3.z + self.z) * di;
    float m0 = 0.f, m1 = 0.f;
#pragma unroll
    for (int k = 0; k < 8; ++k) {
        float h = fmaxf(s0 * W1[k] + s1 * W1[8 + k] + s2 * W1[16 + k] + b1[k], 0.0f);
        m0 += h * W2[2 * k];
        m1 += h * W2[2 * k + 1];
    }
    z[(size_t)i * 2]     = m0 * di;
    z[(size_t)i * 2 + 1] = m1 * di;
}

// F1: split-K LDS accumulation of z[src] -> partial2[sp][node] (float2).
__global__ void agg2_partial_kernel(const unsigned int* __restrict__ sorted,
                                    const int* __restrict__ bucketPtr,
                                    const float* __restrict__ z,
                                    float2* __restrict__ partial2, int N) {
    __shared__ float a0[BSZ], a1[BSZ];
    int t = threadIdx.x;
    int bk = blockIdx.x >> 2, sp = blockIdx.x & 3;
    for (int l = t; l < BSZ; l += AGG_THREADS) { a0[l] = 0.f; a1[l] = 0.f; }
    __syncthreads();
    int beg = bucketPtr[bk], end = bucketPtr[bk + 1], len = end - beg;
    int s0 = beg + (int)(((long long)len * sp) >> 2);
    int s1 = beg + (int)(((long long)len * (sp + 1)) >> 2);
    for (int j = s0 + t; j < s1; j += AGG_THREADS) {
        unsigned int rec = sorted[j];
        int s = rec >> SHIFT;
        int ld = rec & (BSZ - 1);
        float2 zv = *(const float2*)(z + (size_t)s * 2);
        atomicAdd(&a0[ld], zv.x);
        atomicAdd(&a1[ld], zv.y);
    }
    __syncthreads();
    size_t base = (size_t)sp * N;
    for (int l = t; l < BSZ; l += AGG_THREADS) {
        int i = (bk << SHIFT) + l;
        if (i < N) partial2[base + i] = make_float2(a0[l], a1[l]);
    }
}

// F2: sum partials + self -> out.
__global__ void out_epilogue_kernel(const float2* __restrict__ partial2,
                                    const float* __restrict__ z, const float* __restrict__ dinv,
                                    const float* __restrict__ b2, float* __restrict__ out, int N) {
    int i = blockIdx.x * blockDim.x + threadIdx.x;
    if (i >= N) return;
    float2 p0 = partial2[i];
    float2 p1 = partial2[(size_t)N + i];
    float2 p2 = partial2[2 * (size_t)N + i];
    float2 p3 = partial2[3 * (size_t)N + i];
    const float2 zs = *(const float2*)(z + (size_t)i * 2);
    float di = dinv[i];
    out[(size_t)i * 2]     = di * (p0.x + p1.x + p2.x + p3.x + zs.x) + b2[0];
    out[(size_t)i * 2 + 1] = di * (p0.y + p1.y + p2.y + p3.y + zs.y) + b2[1];
}

extern "C" void kernel_launch(void* const* d_in, const int* in_sizes, int n_in,
                              void* d_out, int out_size, void* d_ws, size_t ws_size,
                              hipStream_t stream) {
    const float* x  = (const float*)d_in[0];
    const int*   ei = (const int*)d_in[1];   // [2, E] flat: src row, dst row
    const float* W1 = (const float*)d_in[2];
    const float* b1 = (const float*)d_in[3];
    const float* W2 = (const float*)d_in[4];
    const float* b2 = (const float*)d_in[5];
    float* out = (float*)d_out;

    const int N = in_sizes[0] / 3;
    const int E = in_sizes[1] / 2;
    const int NBK = (N + BSZ - 1) / BSZ;       // 245 buckets
    const int NBA = (E + CH - 1) / CH;         // 977 blocks in A/C

    // Workspace carve-up. `scratch` (4*N*16 B = 32 MB) is reused sequentially:
    // partialD (D1->D2), then partial1 (E1->E2), then partial2 (F1->F2).
    char* ws = (char*)d_ws;
    size_t off = 0;
    auto alloc = [&](size_t bytes) { char* p = ws + off; off = (off + bytes + 15) & ~(size_t)15; return p; };
    int* histM           = (int*)alloc((size_t)NBK * NBA * 4);
    int* totals          = (int*)alloc((size_t)NBK * 4);
    int* bucketPtr       = (int*)alloc(((size_t)NBK + 1) * 4);
    char* scratch        = alloc((size_t)SPLIT * N * 16);
    float* dinv          = (float*)alloc((size_t)N * 4);
    float* z             = (float*)alloc((size_t)N * 8);
    float4* xd4          = (float4*)alloc((size_t)N * 16);
    unsigned int* sorted = (unsigned int*)alloc((size_t)E * 4);
    (void)ws_size;

    int* partialD    = (int*)scratch;
    float4* partial1 = (float4*)scratch;
    float2* partial2 = (float2*)scratch;

    const int nb = (N + 255) / 256;

    bucket_count_kernel<<<NBA, 256, 0, stream>>>(ei + E, histM, E, NBA, NBK);
    colscan_kernel<<<NBK, 256, 0, stream>>>(histM, totals, NBA);
    bucketscan_kernel<<<1, 256, 0, stream>>>(totals, bucketPtr, NBK, E);
    bucket_scatter_kernel<<<NBA, 256, 0, stream>>>(ei, histM, bucketPtr, sorted, E, NBA, NBK);
    deg_partial_kernel<<<NBK * SPLIT, AGG_THREADS, 0, stream>>>(sorted, bucketPtr, partialD, N);
    dinv_xd_kernel<<<nb, 256, 0, stream>>>(partialD, x, dinv, xd4, N);
    agg1_partial_kernel<<<NBK * SPLIT, AGG_THREADS, 0, stream>>>(sorted, bucketPtr, xd4, partial1, N);
    z_epilogue_kernel<<<nb, 256, 0, stream>>>(partial1, xd4, dinv, W1, b1, W2, z, N);
    agg2_partial_kernel<<<NBK * SPLIT, AGG_THREADS, 0, stream>>>(sorted, bucketPtr, z, partial2, N);
    out_epilogue_kernel<<<nb, 256, 0, stream>>>(partial2, z, dinv, b2, out, N);
}